// Round 7
// baseline (542.284 us; speedup 1.0000x reference)
//
#include <hip/hip_runtime.h>

typedef __bf16 bf16;
typedef bf16 bf16x8 __attribute__((ext_vector_type(8)));
typedef float f32x4 __attribute__((ext_vector_type(4)));
typedef unsigned int uint;
typedef uint u32x4 __attribute__((ext_vector_type(4)));
typedef unsigned short u16x8 __attribute__((ext_vector_type(8)));

constexpr int NT = 4096;   // sequence length N
// H = 64, B = 2

__device__ __forceinline__ bf16x8 ld8f(const float* p) {
    f32x4 a = *(const f32x4*)p;
    f32x4 b = *(const f32x4*)(p + 4);
    bf16x8 v;
    v[0] = (bf16)a[0]; v[1] = (bf16)a[1]; v[2] = (bf16)a[2]; v[3] = (bf16)a[3];
    v[4] = (bf16)b[0]; v[5] = (bf16)b[1]; v[6] = (bf16)b[2]; v[7] = (bf16)b[3];
    return v;
}

__device__ __forceinline__ uint pack2(float a, float b) {
    unsigned short ua = __builtin_bit_cast(unsigned short, (bf16)a);
    unsigned short ub = __builtin_bit_cast(unsigned short, (bf16)b);
    return (uint)ua | ((uint)ub << 16);
}

// ---------------------------------------------------------------------------
// Kernel 1: grid = 1536. slices 0..8: one projection each (q0,q1,q2,k0..k5);
// slices 9..11: bf16 transpose vT for one pred each.
// ---------------------------------------------------------------------------
__global__ __launch_bounds__(256) void prep_kernel(
    const float* __restrict__ h0, const float* __restrict__ h1, const float* __restrict__ h2,
    const float* __restrict__ Wq, const float* __restrict__ Wk,
    bf16* __restrict__ qn, bf16* __restrict__ kn, bf16* __restrict__ vT)
{
    __shared__ __align__(16) unsigned short tlds[4][16][72];
    const int tid = threadIdx.x, wid = tid >> 6, lane = tid & 63;
    const int l15 = lane & 15, quad = lane >> 4;
    const int bx = blockIdx.x;
    const int rt = bx & 127, sl = bx >> 7;       // slice 0..11
    const int g0 = rt * 64;
    const int grow = g0 + wid * 16 + l15;        // A-frag row (global b*N+n)
    const float* hs[3] = {h0, h1, h2};
    const int predmap[6] = {0, 2, 0, 1, 1, 2};

    if (sl >= 9) {
        // ---- transpose slice: vT[p][b][h][n] ----
        const int p = sl - 9;
        bf16x8 af[2];
#pragma unroll
        for (int hc = 0; hc < 2; hc++)
            af[hc] = ld8f(hs[p] + (size_t)grow * 64 + hc * 32 + quad * 8);
#pragma unroll
        for (int hc = 0; hc < 2; hc++)
            *(u16x8*)(&tlds[wid][l15][hc * 32 + quad * 8]) = __builtin_bit_cast(u16x8, af[hc]);
        unsigned short vals[16];
#pragma unroll
        for (int r = 0; r < 16; r++) vals[r] = tlds[wid][r][lane];
        uint us[8];
#pragma unroll
        for (int k = 0; k < 8; k++) us[k] = (uint)vals[2 * k] | ((uint)vals[2 * k + 1] << 16);
        const int gr0 = g0 + wid * 16;
        const int bb = gr0 >> 12, n0 = gr0 & 4095;
        uint* dst = (uint*)(vT + ((size_t)(p * 2 + bb) * 64 + lane) * NT + n0);
        u32x4 w0 = {us[0], us[1], us[2], us[3]};
        u32x4 w1 = {us[4], us[5], us[6], us[7]};
        *(u32x4*)dst = w0;
        *(u32x4*)(dst + 4) = w1;
        return;
    }

    // ---- projection slice ----
    const int pj = sl;
    const float* W = (pj < 3) ? (Wq + pj * 4096) : (Wk + (pj - 3) * 4096);
    const int src = (pj < 3) ? pj : predmap[pj - 3];
    bf16* outp = (pj < 3) ? (qn + (size_t)pj * 2 * NT * 64)
                          : (kn + (size_t)(pj - 3) * 2 * NT * 64);
    bf16x8 af[2];
#pragma unroll
    for (int hc = 0; hc < 2; hc++)
        af[hc] = ld8f(hs[src] + (size_t)grow * 64 + hc * 32 + quad * 8);

    f32x4 s[4];
#pragma unroll
    for (int it = 0; it < 4; it++) {
        f32x4 acc = {0.f, 0.f, 0.f, 0.f};
#pragma unroll
        for (int hc = 0; hc < 2; hc++) {
            bf16x8 wb = ld8f(W + (size_t)(it * 16 + l15) * 64 + hc * 32 + quad * 8);
            acc = __builtin_amdgcn_mfma_f32_16x16x32_bf16(af[hc], wb, acc, 0, 0, 0);
        }
        s[it] = acc;
    }
#pragma unroll
    for (int r = 0; r < 4; r++) {
        float ss = s[0][r] * s[0][r] + s[1][r] * s[1][r] + s[2][r] * s[2][r] + s[3][r] * s[3][r];
        ss += __shfl_xor(ss, 1); ss += __shfl_xor(ss, 2);
        ss += __shfl_xor(ss, 4); ss += __shfl_xor(ss, 8);
        float rn = rsqrtf(ss);
        s[0][r] *= rn; s[1][r] *= rn; s[2][r] *= rn; s[3][r] *= rn;
    }
    const int rowbase = g0 + wid * 16 + quad * 4;
#pragma unroll
    for (int it = 0; it < 4; it++)
#pragma unroll
        for (int r = 0; r < 4; r++)
            outp[(size_t)(rowbase + r) * 64 + it * 16 + l15] = (bf16)s[it][r];
}

// ---------------------------------------------------------------------------
// Kernel 2: masked cosine attention, FUSED raw-fp32-mask version (R1 base):
//   - full batch per block (mask elements read exactly once overall)
//   - mask loads for iter ji+1 issued at the TOP of iter ji (2-set mvA/mvB
//     rotation via 2-phase unrolled loop -> static register naming);
//     issue->use gap ~1.3 iterations keeps the 402MB stream continuously
//     outstanding, overlapped with MFMA/LDS compute.
//   - single LDS buffer, 2 barriers (R1), reg-staged K/V 1 iter ahead
//   - permlane B-frag exchange; Pacc [chunk][e][b][n][h] f32x4 stores
//   - in-kernel mask rowsums -> rsO[chunk][e][n]
// grid = 6 edges * 32 q-tiles(128 rows) * JC, XCD-swizzled.
// ---------------------------------------------------------------------------
template<int JC>
__global__ __launch_bounds__(256, 2) void attn_kernel(
    const bf16* __restrict__ qn, const bf16* __restrict__ kn, const bf16* __restrict__ vT,
    const float* __restrict__ m00, const float* __restrict__ m20, const float* __restrict__ m01,
    const float* __restrict__ m11, const float* __restrict__ m12, const float* __restrict__ m22,
    float* __restrict__ Pacc, float* __restrict__ rsO)
{
    __shared__ __align__(16) bf16 Klds[2][64][72];
    __shared__ __align__(16) bf16 Vlds[2][64][72];
    const int tid = threadIdx.x, wid = tid >> 6, lane = tid & 63;
    const int l15 = lane & 15, quad = lane >> 4;
    constexpr int G = 6 * 32 * JC;
    const int bxr = blockIdx.x;
    const int wg = (bxr & 7) * (G >> 3) + (bxr >> 3);   // bijective: G%8==0
    const int jcv = wg % JC;
    int r = wg / JC;
    const int qt = r & 31; const int e = r >> 5;
    const int qtypemap[6] = {0, 0, 1, 1, 2, 2};
    const int predmap[6]  = {0, 2, 0, 1, 1, 2};
    const float* masks[6] = {m00, m20, m01, m11, m12, m22};
    const float* __restrict__ mask = masks[e];
    const int qtv = qtypemap[e], pv = predmap[e];
    const int qrow0 = qt * 128, wstrip = wid * 32;
    constexpr int JSPAN = NT / JC;
    constexpr int NI = JSPAN / 64;                      // even for JC in {1,2,4}
    const int jbeg = jcv * JSPAN;

    // per-thread staging line mapping (4 K lines + 4 V lines per thread)
    int s_b[4], s_jl[4], s_ch[4];
#pragma unroll
    for (int i = 0; i < 4; i++) {
        int u = tid + 256 * i;
        s_b[i] = u >> 9; s_jl[i] = (u >> 3) & 63; s_ch[i] = u & 7;
    }

    // Q fragments (stage-1 B-operand), register resident
    bf16x8 Qf[2][2][2];
#pragma unroll
    for (int b = 0; b < 2; b++)
#pragma unroll
        for (int mt = 0; mt < 2; mt++)
#pragma unroll
            for (int hc = 0; hc < 2; hc++)
                Qf[b][mt][hc] = *(const bf16x8*)(qn +
                    ((size_t)(qtv * 2 + b) * NT + qrow0 + wstrip + mt * 16 + l15) * 64 +
                    hc * 32 + quad * 8);

    f32x4 acc2[2][4][2];   // [b][ht][mt]  (acc^T: row=h, col=query)
#pragma unroll
    for (int b = 0; b < 2; b++)
#pragma unroll
        for (int ht = 0; ht < 4; ht++)
#pragma unroll
            for (int mt = 0; mt < 2; mt++) {
                f32x4 z = {0.f, 0.f, 0.f, 0.f};
                acc2[b][ht][mt] = z;
            }
    float rsl[2] = {0.f, 0.f};

    // ---- prologue: stage regs + masks for iteration 0 ----
    u32x4 kreg[4], vreg[4];
#pragma unroll
    for (int i = 0; i < 4; i++) {
        kreg[i] = *(const u32x4*)(kn + ((size_t)(e * 2 + s_b[i]) * NT + jbeg + s_jl[i]) * 64 + s_ch[i] * 8);
        vreg[i] = *(const u32x4*)(vT + ((size_t)(pv * 2 + s_b[i]) * 64 + s_jl[i]) * NT + jbeg + s_ch[i] * 8);
    }
    f32x4 mvA[2][4], mvB[2][4];
#pragma unroll
    for (int mt = 0; mt < 2; mt++)
#pragma unroll
        for (int jt = 0; jt < 4; jt++)
            mvA[mt][jt] = *(const f32x4*)(mask +
                (size_t)(qrow0 + wstrip + mt * 16 + l15) * NT + jbeg + jt * 16 + quad * 4);

    auto body = [&](int ji, f32x4 (&cur)[2][4], f32x4 (&nxt)[2][4]) {
        const int jn = (ji + 1 < NI) ? (ji + 1) * 64 : 0;   // next tile offset (clamped)

        // 1. issue NEXT iteration's mask loads first (longest latency, HBM)
#pragma unroll
        for (int mt = 0; mt < 2; mt++)
#pragma unroll
            for (int jt = 0; jt < 4; jt++)
                nxt[mt][jt] = *(const f32x4*)(mask +
                    (size_t)(qrow0 + wstrip + mt * 16 + l15) * NT + jbeg + jn + jt * 16 + quad * 4);

        // 2. stage K/V tile into LDS
        __syncthreads();                           // prior compute done reading LDS
#pragma unroll
        for (int i = 0; i < 4; i++) {
            *(u32x4*)(&Klds[s_b[i]][s_jl[i]][s_ch[i] * 8]) = kreg[i];
            *(u32x4*)(&Vlds[s_b[i]][s_jl[i]][s_ch[i] * 8]) = vreg[i];
        }
        __syncthreads();                           // staged tile visible

        // 3. issue next iteration's K/V staging loads (L2/L3-resident)
#pragma unroll
        for (int i = 0; i < 4; i++) {
            kreg[i] = *(const u32x4*)(kn + ((size_t)(e * 2 + s_b[i]) * NT + jbeg + jn + s_jl[i]) * 64 + s_ch[i] * 8);
            vreg[i] = *(const u32x4*)(vT + ((size_t)(pv * 2 + s_b[i]) * 64 + s_jl[i]) * NT + jbeg + jn + s_ch[i] * 8);
        }

        // 4. mask rowsums (current set)
#pragma unroll
        for (int mt = 0; mt < 2; mt++)
#pragma unroll
            for (int jt = 0; jt < 4; jt++)
                rsl[mt] += cur[mt][jt][0] + cur[mt][jt][1] + cur[mt][jt][2] + cur[mt][jt][3];

        // 5. stage 1 for BOTH batches: S^T tiles, mask multiply, pack bf16
        uint Pd[2][4][2][2];    // [b][jt][mt][d]
#pragma unroll
        for (int jt = 0; jt < 4; jt++)
#pragma unroll
            for (int b = 0; b < 2; b++) {
                bf16x8 aK0 = *(const bf16x8*)(&Klds[b][jt * 16 + l15][quad * 8]);
                bf16x8 aK1 = *(const bf16x8*)(&Klds[b][jt * 16 + l15][32 + quad * 8]);
#pragma unroll
                for (int mt = 0; mt < 2; mt++) {
                    f32x4 sc = {0.f, 0.f, 0.f, 0.f};
                    sc = __builtin_amdgcn_mfma_f32_16x16x32_bf16(aK0, Qf[b][mt][0], sc, 0, 0, 0);
                    sc = __builtin_amdgcn_mfma_f32_16x16x32_bf16(aK1, Qf[b][mt][1], sc, 0, 0, 0);
                    sc[0] *= cur[mt][jt][0]; sc[1] *= cur[mt][jt][1];
                    sc[2] *= cur[mt][jt][2]; sc[3] *= cur[mt][jt][3];
                    Pd[b][jt][mt][0] = pack2(sc[0], sc[1]);
                    Pd[b][jt][mt][1] = pack2(sc[2], sc[3]);
                }
            }

        // 6+7. per batch: B-frags via permlane row-swaps, then acc^T += VT·P^T
#pragma unroll
        for (int b = 0; b < 2; b++) {
            uint Bf[2][2][4];    // [mt][c][v]
#pragma unroll
            for (int mt = 0; mt < 2; mt++)
#pragma unroll
                for (int c = 0; c < 2; c++)
#pragma unroll
                    for (int d = 0; d < 2; d++) {
                        uint x = Pd[b][2 * c][mt][d];
                        uint y = Pd[b][2 * c + 1][mt][d];
                        asm("v_permlane32_swap_b32 %0, %1\n\t"
                            "v_permlane16_swap_b32 %0, %1"
                            : "+v"(x), "+v"(y));
                        Bf[mt][c][d]     = x;   // v = d
                        Bf[mt][c][d + 2] = y;   // v = d+2
                    }
#pragma unroll
            for (int ht = 0; ht < 4; ht++)
#pragma unroll
                for (int c = 0; c < 2; c++) {
                    bf16x8 a = *(const bf16x8*)(&Vlds[b][ht * 16 + l15][c * 32 + quad * 8]);
#pragma unroll
                    for (int mt = 0; mt < 2; mt++) {
                        u32x4 t = {Bf[mt][c][0], Bf[mt][c][1], Bf[mt][c][2], Bf[mt][c][3]};
                        bf16x8 bbv = __builtin_bit_cast(bf16x8, t);
                        acc2[b][ht][mt] =
                            __builtin_amdgcn_mfma_f32_16x16x32_bf16(a, bbv, acc2[b][ht][mt], 0, 0, 0);
                    }
                }
        }
    };

#pragma unroll 1
    for (int ji2 = 0; ji2 < NI; ji2 += 2) {
        body(ji2,     mvA, mvB);
        body(ji2 + 1, mvB, mvA);
    }

    // vectorized fp32 partial store: Pacc[chunk][e][b][n][h], one f32x4/frag
#pragma unroll
    for (int b = 0; b < 2; b++)
#pragma unroll
        for (int ht = 0; ht < 4; ht++)
#pragma unroll
            for (int mt = 0; mt < 2; mt++) {
                const int n = qrow0 + wstrip + mt * 16 + l15;
                *(f32x4*)(Pacc + ((((size_t)(jcv * 6 + e) * 2 + b) * NT + n) << 6) +
                          ht * 16 + quad * 4) = acc2[b][ht][mt];
            }
    // mask rowsums: quads hold disjoint j segments
#pragma unroll
    for (int mt = 0; mt < 2; mt++) {
        float v = rsl[mt];
        v += __shfl_xor(v, 16);
        v += __shfl_xor(v, 32);
        if (quad == 0)
            rsO[(size_t)(jcv * 6 + e) * NT + qrow0 + wstrip + mt * 16 + l15] = v;
    }
}

// ---------------------------------------------------------------------------
// Kernel 3: combine fp32 partials over JC chunks (acc_t = ΣP/Σrs per edge),
// dt_t = 2*sigmoid(h_t Wdt_t^T + b) - 1, h_tn = h_t + step*dt*u_t, outputs.
// Output columns split across 2 blocks (ih), grid 768.
// ---------------------------------------------------------------------------
template<int JC>
__global__ __launch_bounds__(256) void update_kernel(
    const float* __restrict__ x0, const float* __restrict__ h0,
    const float* __restrict__ h1, const float* __restrict__ h2,
    const float* __restrict__ Wsu0, const float* __restrict__ Wsu12,
    const float* __restrict__ Wdt, const float* __restrict__ bdt,
    const float* __restrict__ stepp, const float* __restrict__ oscp,
    const float* __restrict__ Pacc, const float* __restrict__ rs,
    float* __restrict__ dout)
{
    const int tid = threadIdx.x, wid = tid >> 6, lane = tid & 63;
    const int l15 = lane & 15, quad = lane >> 4;
    const int bx = blockIdx.x;
    const int ih = (bx >= 384) ? 1 : 0;          // column half: it = ih*2 + ii
    const int base = bx - ih * 384;              // 0..383
    const int rt = base & 127, t = base >> 7;
    const int g0 = rt * 64;
    const int grow = g0 + wid * 16 + l15;
    const int n = grow & 4095, bb = grow >> 12;
    const float step = *stepp, osc = *oscp;
    const float* hs[3] = {h0, h1, h2};
    const float* __restrict__ ht_base = hs[t];

    bf16x8 afh[2], afacc[2], afx;
#pragma unroll
    for (int hc = 0; hc < 2; hc++)
        afh[hc] = ld8f(ht_base + (size_t)grow * 64 + hc * 32 + quad * 8);
    if (t == 0) afx = ld8f(x0 + (size_t)grow * 32 + quad * 8);

    float s0 = 0.f, s1 = 0.f;
#pragma unroll
    for (int jc = 0; jc < JC; jc++) {
        s0 += rs[(size_t)(jc * 6 + 2 * t) * NT + n];
        s1 += rs[(size_t)(jc * 6 + 2 * t + 1) * NT + n];
    }
    const float i0 = 1.f / s0, i1 = 1.f / s1;
#pragma unroll
    for (int hc = 0; hc < 2; hc++) {
        f32x4 S0a = {0.f,0.f,0.f,0.f}, S0b = {0.f,0.f,0.f,0.f};
        f32x4 S1a = {0.f,0.f,0.f,0.f}, S1b = {0.f,0.f,0.f,0.f};
#pragma unroll
        for (int jc = 0; jc < JC; jc++) {
            const float* p0 = Pacc + ((((size_t)(jc * 6 + 2 * t) * 2 + bb) * NT + n) << 6) +
                              hc * 32 + quad * 8;
            const float* p1 = Pacc + ((((size_t)(jc * 6 + 2 * t + 1) * 2 + bb) * NT + n) << 6) +
                              hc * 32 + quad * 8;
            S0a += *(const f32x4*)p0;  S0b += *(const f32x4*)(p0 + 4);
            S1a += *(const f32x4*)p1;  S1b += *(const f32x4*)(p1 + 4);
        }
        bf16x8 v;
#pragma unroll
        for (int j = 0; j < 4; j++) v[j]     = (bf16)(S0a[j] * i0 + S1a[j] * i1);
#pragma unroll
        for (int j = 0; j < 4; j++) v[4 + j] = (bf16)(S0b[j] * i0 + S1b[j] * i1);
        afacc[hc] = v;
    }

#pragma unroll
    for (int ii = 0; ii < 2; ii++) {
        const int it = ih * 2 + ii;
        const float bdtv = bdt[t * 64 + it * 16 + l15];
        f32x4 z = {0.f, 0.f, 0.f, 0.f};
        f32x4 u = {0.f, 0.f, 0.f, 0.f};
#pragma unroll
        for (int hc = 0; hc < 2; hc++) {
            bf16x8 wb = ld8f(Wdt + (size_t)t * 4096 + (size_t)(it * 16 + l15) * 64 + hc * 32 + quad * 8);
            z = __builtin_amdgcn_mfma_f32_16x16x32_bf16(afh[hc], wb, z, 0, 0, 0);
        }
        if (t == 0) {
            bf16x8 w0 = ld8f(Wsu0 + (size_t)(it * 16 + l15) * 96 + quad * 8);
            u = __builtin_amdgcn_mfma_f32_16x16x32_bf16(afx, w0, u, 0, 0, 0);
#pragma unroll
            for (int kc = 0; kc < 2; kc++) {
                bf16x8 wk = ld8f(Wsu0 + (size_t)(it * 16 + l15) * 96 + 32 + kc * 32 + quad * 8);
                u = __builtin_amdgcn_mfma_f32_16x16x32_bf16(afacc[kc], wk, u, 0, 0, 0);
            }
        } else {
#pragma unroll
            for (int kc = 0; kc < 2; kc++) {
                bf16x8 wk = ld8f(Wsu12 + (size_t)(t - 1) * 4096 + (size_t)(it * 16 + l15) * 64 + kc * 32 + quad * 8);
                u = __builtin_amdgcn_mfma_f32_16x16x32_bf16(afacc[kc], wk, u, 0, 0, 0);
            }
        }
        const int colg = it * 16 + l15;
#pragma unroll
        for (int r = 0; r < 4; r++) {
            int row = g0 + wid * 16 + quad * 4 + r;
            float zz = z[r] + bdtv;
            float dtv = 2.f / (1.f + __expf(-zz)) - 1.f;
            float hval = ht_base[(size_t)row * 64 + colg];
            float hn = hval + step * dtv * u[r];
            dout[65536 + (size_t)t * 524288 + (size_t)row * 64 + colg] = hn;
            if (t == 2 && colg < 8)
                dout[(size_t)row * 8 + colg] = osc * hn;
        }
    }
}

extern "C" void kernel_launch(void* const* d_in, const int* in_sizes, int n_in,
                              void* d_out, int out_size, void* d_ws, size_t ws_size,
                              hipStream_t stream) {
    const float* x0   = (const float*)d_in[0];
    const float* h0   = (const float*)d_in[1];
    const float* h1   = (const float*)d_in[2];
    const float* h2   = (const float*)d_in[3];
    const float* m00  = (const float*)d_in[4];
    const float* m20  = (const float*)d_in[5];
    const float* m01  = (const float*)d_in[6];
    const float* m11  = (const float*)d_in[7];
    const float* m12  = (const float*)d_in[8];
    const float* m22  = (const float*)d_in[9];
    const float* Wq   = (const float*)d_in[10];
    const float* Wk   = (const float*)d_in[11];
    const float* Wsu0 = (const float*)d_in[12];
    const float* Wsu12= (const float*)d_in[13];
    const float* Wdt  = (const float*)d_in[14];
    const float* bdt  = (const float*)d_in[15];
    const float* step = (const float*)d_in[16];
    const float* oscl = (const float*)d_in[17];

    // workspace layout (element counts)
    bf16* qn  = (bf16*)d_ws;                    // 3*2*4096*64 = 1,572,864
    bf16* kn  = qn + 1572864;                   // 6*2*4096*64 = 3,145,728
    bf16* vT  = kn + 3145728;                   // 3*2*64*4096 = 1,572,864
    float* rs = (float*)(vT + 1572864);         // JC*6*4096 floats
    // Pacc follows rs: JC*6*2*4096*64 floats [chunk][e][b][n][h]

    // bytes: 12,582,912 fixed + JC*98,304 (rs) + JC*12,582,912 (Pacc)
    auto need = [](size_t jc) { return 12582912 + jc * 98304 + jc * 12582912; };
    const int JC = (ws_size >= need(4)) ? 4 : ((ws_size >= need(2)) ? 2 : 1);
    float* Pacc = rs + (size_t)JC * 24576;

    prep_kernel<<<1536, 256, 0, stream>>>(h0, h1, h2, Wq, Wk, qn, kn, vT);

    if (JC == 4) {
        attn_kernel<4><<<6 * 32 * 4, 256, 0, stream>>>(qn, kn, vT, m00, m20, m01, m11, m12, m22, Pacc, rs);
        update_kernel<4><<<768, 256, 0, stream>>>(x0, h0, h1, h2, Wsu0, Wsu12, Wdt, bdt,
                                                  step, oscl, Pacc, rs, (float*)d_out);
    } else if (JC == 2) {
        attn_kernel<2><<<6 * 32 * 2, 256, 0, stream>>>(qn, kn, vT, m00, m20, m01, m11, m12, m22, Pacc, rs);
        update_kernel<2><<<768, 256, 0, stream>>>(x0, h0, h1, h2, Wsu0, Wsu12, Wdt, bdt,
                                                  step, oscl, Pacc, rs, (float*)d_out);
    } else {
        attn_kernel<1><<<6 * 32 * 1, 256, 0, stream>>>(qn, kn, vT, m00, m20, m01, m11, m12, m22, Pacc, rs);
        update_kernel<1><<<768, 256, 0, stream>>>(x0, h0, h1, h2, Wsu0, Wsu12, Wdt, bdt,
                                                  step, oscl, Pacc, rs, (float*)d_out);
    }
}

// Round 8
// 475.792 us; speedup vs baseline: 1.1397x; 1.1397x over previous
//
#include <hip/hip_runtime.h>

typedef __bf16 bf16;
typedef bf16 bf16x8 __attribute__((ext_vector_type(8)));
typedef float f32x4 __attribute__((ext_vector_type(4)));
typedef unsigned int uint;
typedef uint u32x2 __attribute__((ext_vector_type(2)));
typedef uint u32x4 __attribute__((ext_vector_type(4)));
typedef unsigned short u16x4 __attribute__((ext_vector_type(4)));
typedef unsigned short u16x8 __attribute__((ext_vector_type(8)));

constexpr int NT = 4096;   // sequence length N
// H = 64, B = 2

__device__ __forceinline__ bf16x8 ld8f(const float* p) {
    f32x4 a = *(const f32x4*)p;
    f32x4 b = *(const f32x4*)(p + 4);
    bf16x8 v;
    v[0] = (bf16)a[0]; v[1] = (bf16)a[1]; v[2] = (bf16)a[2]; v[3] = (bf16)a[3];
    v[4] = (bf16)b[0]; v[5] = (bf16)b[1]; v[6] = (bf16)b[2]; v[7] = (bf16)b[3];
    return v;
}

__device__ __forceinline__ uint pack2(float a, float b) {
    unsigned short ua = __builtin_bit_cast(unsigned short, (bf16)a);
    unsigned short ub = __builtin_bit_cast(unsigned short, (bf16)b);
    return (uint)ua | ((uint)ub << 16);
}

// ---------------------------------------------------------------------------
// Kernel 0: mask bit-pack. One row per wave; TWO f32x4 loads per lane per
// iteration (2KB/wave/iter, ring of 4 pairs -> ~8KB/wave in flight), 8 iters.
// Iteration 'it' covers j in [512it, 512it+512): group A = first 256
// (j = 512it + 4p + c), group B = second 256 (j = 512it + 256 + 4p + c).
// Lane l owns block [64l, 64l+64): it = l>>3; q = l&7; group A if q<4 else B;
// ballot 16-bit field shift s = (q&3)*16. Stored bit layout per block
// (consumed by attn): word = c>>1, bit = (c&1)*16 + p' — unchanged from R6.
// ---------------------------------------------------------------------------
__global__ __launch_bounds__(256) void mask_kernel(
    const float* __restrict__ m00, const float* __restrict__ m20, const float* __restrict__ m01,
    const float* __restrict__ m11, const float* __restrict__ m12, const float* __restrict__ m22,
    uint* __restrict__ mb, float* __restrict__ rs2)
{
    const int tid = threadIdx.x, wid = tid >> 6, lane = tid & 63;
    const int mi = blockIdx.x;
    const int e = mi >> 10, rb = mi & 1023;
    const int row = rb * 4 + wid;
    const float* masks[6] = {m00, m20, m01, m11, m12, m22};
    const float* mrow = masks[e] + (size_t)row * NT;
    const int own_it = lane >> 3;
    const int q = lane & 7;
    const uint s = (uint)(q & 3) * 16;

    f32x4 bufA[4], bufB[4];
#pragma unroll
    for (int p = 0; p < 4; p++) {
        bufA[p] = *(const f32x4*)(mrow + 512 * p + 4 * lane);
        bufB[p] = *(const f32x4*)(mrow + 512 * p + 256 + 4 * lane);
    }

    uint lo = 0, hi = 0, cnt = 0;
#pragma unroll
    for (int it = 0; it < 8; it++) {
        f32x4 vA = bufA[it & 3], vB = bufB[it & 3];
        if (it + 4 < 8) {
            bufA[it & 3] = *(const f32x4*)(mrow + 512 * (it + 4) + 4 * lane);
            bufB[it & 3] = *(const f32x4*)(mrow + 512 * (it + 4) + 256 + 4 * lane);
        }
        unsigned long long a0 = __ballot(vA[0] > 0.5f);
        unsigned long long a1 = __ballot(vA[1] > 0.5f);
        unsigned long long a2 = __ballot(vA[2] > 0.5f);
        unsigned long long a3 = __ballot(vA[3] > 0.5f);
        unsigned long long b0 = __ballot(vB[0] > 0.5f);
        unsigned long long b1 = __ballot(vB[1] > 0.5f);
        unsigned long long b2 = __ballot(vB[2] > 0.5f);
        unsigned long long b3 = __ballot(vB[3] > 0.5f);
        cnt += __popcll(a0) + __popcll(a1) + __popcll(a2) + __popcll(a3)
             + __popcll(b0) + __popcll(b1) + __popcll(b2) + __popcll(b3);
        uint loA = ((uint)(a0 >> s) & 0xFFFFu) | (((uint)(a1 >> s) & 0xFFFFu) << 16);
        uint hiA = ((uint)(a2 >> s) & 0xFFFFu) | (((uint)(a3 >> s) & 0xFFFFu) << 16);
        uint loB = ((uint)(b0 >> s) & 0xFFFFu) | (((uint)(b1 >> s) & 0xFFFFu) << 16);
        uint hiB = ((uint)(b2 >> s) & 0xFFFFu) | (((uint)(b3 >> s) & 0xFFFFu) << 16);
        uint lox = (q < 4) ? loA : loB;
        uint hix = (q < 4) ? hiA : hiB;
        if (own_it == it) { lo = lox; hi = hix; }
    }
    if (lane == 0) rs2[e * NT + row] = (float)cnt;
    u32x2 w = {lo, hi};
    ((u32x2*)(mb + (size_t)(e * NT + row) * 128))[lane] = w;
}

// ---------------------------------------------------------------------------
// Kernel 1: grid = 1536. slices 0..8: one projection each (q0,q1,q2,k0..k5);
// slices 9..11: bf16 transpose vT for one pred each.
// ---------------------------------------------------------------------------
__global__ __launch_bounds__(256) void prep_kernel(
    const float* __restrict__ h0, const float* __restrict__ h1, const float* __restrict__ h2,
    const float* __restrict__ Wq, const float* __restrict__ Wk,
    bf16* __restrict__ qn, bf16* __restrict__ kn, bf16* __restrict__ vT)
{
    __shared__ __align__(16) unsigned short tlds[4][16][72];
    const int tid = threadIdx.x, wid = tid >> 6, lane = tid & 63;
    const int l15 = lane & 15, quad = lane >> 4;
    const int bx = blockIdx.x;
    const int rt = bx & 127, sl = bx >> 7;       // slice 0..11
    const int g0 = rt * 64;
    const int grow = g0 + wid * 16 + l15;        // A-frag row (global b*N+n)
    const float* hs[3] = {h0, h1, h2};
    const int predmap[6] = {0, 2, 0, 1, 1, 2};

    if (sl >= 9) {
        // ---- transpose slice: vT[p][b][h][n] ----
        const int p = sl - 9;
        bf16x8 af[2];
#pragma unroll
        for (int hc = 0; hc < 2; hc++)
            af[hc] = ld8f(hs[p] + (size_t)grow * 64 + hc * 32 + quad * 8);
#pragma unroll
        for (int hc = 0; hc < 2; hc++)
            *(u16x8*)(&tlds[wid][l15][hc * 32 + quad * 8]) = __builtin_bit_cast(u16x8, af[hc]);
        unsigned short vals[16];
#pragma unroll
        for (int r = 0; r < 16; r++) vals[r] = tlds[wid][r][lane];
        uint us[8];
#pragma unroll
        for (int k = 0; k < 8; k++) us[k] = (uint)vals[2 * k] | ((uint)vals[2 * k + 1] << 16);
        const int gr0 = g0 + wid * 16;
        const int bb = gr0 >> 12, n0 = gr0 & 4095;
        uint* dst = (uint*)(vT + ((size_t)(p * 2 + bb) * 64 + lane) * NT + n0);
        u32x4 w0 = {us[0], us[1], us[2], us[3]};
        u32x4 w1 = {us[4], us[5], us[6], us[7]};
        *(u32x4*)dst = w0;
        *(u32x4*)(dst + 4) = w1;
        return;
    }

    // ---- projection slice ----
    const int pj = sl;
    const float* W = (pj < 3) ? (Wq + pj * 4096) : (Wk + (pj - 3) * 4096);
    const int src = (pj < 3) ? pj : predmap[pj - 3];
    bf16* outp = (pj < 3) ? (qn + (size_t)pj * 2 * NT * 64)
                          : (kn + (size_t)(pj - 3) * 2 * NT * 64);
    bf16x8 af[2];
#pragma unroll
    for (int hc = 0; hc < 2; hc++)
        af[hc] = ld8f(hs[src] + (size_t)grow * 64 + hc * 32 + quad * 8);

    f32x4 s[4];
#pragma unroll
    for (int it = 0; it < 4; it++) {
        f32x4 acc = {0.f, 0.f, 0.f, 0.f};
#pragma unroll
        for (int hc = 0; hc < 2; hc++) {
            bf16x8 wb = ld8f(W + (size_t)(it * 16 + l15) * 64 + hc * 32 + quad * 8);
            acc = __builtin_amdgcn_mfma_f32_16x16x32_bf16(af[hc], wb, acc, 0, 0, 0);
        }
        s[it] = acc;
    }
#pragma unroll
    for (int r = 0; r < 4; r++) {
        float ss = s[0][r] * s[0][r] + s[1][r] * s[1][r] + s[2][r] * s[2][r] + s[3][r] * s[3][r];
        ss += __shfl_xor(ss, 1); ss += __shfl_xor(ss, 2);
        ss += __shfl_xor(ss, 4); ss += __shfl_xor(ss, 8);
        float rn = rsqrtf(ss);
        s[0][r] *= rn; s[1][r] *= rn; s[2][r] *= rn; s[3][r] *= rn;
    }
    const int rowbase = g0 + wid * 16 + quad * 4;
#pragma unroll
    for (int it = 0; it < 4; it++)
#pragma unroll
        for (int r = 0; r < 4; r++)
            outp[(size_t)(rowbase + r) * 64 + it * 16 + l15] = (bf16)s[it][r];
}

// ---------------------------------------------------------------------------
// Kernel 2: masked cosine attention — R6 structure unchanged (double-buffered
// LDS, one barrier/iter, packed bit-masks, batch split, XCD swizzle) except
// the partial store: Pacc is now BF16 [chunk][e][b][n][h], one u16x4 (8B)
// per fragment. grid = 6 edges * 32 q-tiles(128 rows) * 2 batch * JC.
// ---------------------------------------------------------------------------
template<int JC>
__global__ __launch_bounds__(256, 4) void attn_kernel(
    const bf16* __restrict__ qn, const bf16* __restrict__ kn, const bf16* __restrict__ vT,
    const uint* __restrict__ mb, bf16* __restrict__ Pacc)
{
    __shared__ __align__(16) bf16 Klds[2][64][72];
    __shared__ __align__(16) bf16 Vlds[2][64][72];
    const int tid = threadIdx.x, wid = tid >> 6, lane = tid & 63;
    const int l15 = lane & 15, quad = lane >> 4;
    constexpr int G = 6 * 32 * 2 * JC;
    const int bxr = blockIdx.x;
    const int wg = (bxr & 7) * (G >> 3) + (bxr >> 3);   // bijective: G%8==0
    const int jcv = wg % JC;
    int r = wg / JC;
    const int b = r & 1; r >>= 1;
    const int qt = r & 31; const int e = r >> 5;
    const int qtypemap[6] = {0, 0, 1, 1, 2, 2};
    const int predmap[6]  = {0, 2, 0, 1, 1, 2};
    const int qtv = qtypemap[e], pv = predmap[e];
    const int qrow0 = qt * 128, wstrip = wid * 32;
    constexpr int JSPAN = NT / JC;
    constexpr int NI = JSPAN / 64;
    const int jbeg = jcv * JSPAN;

    // staging map: 2 K lines + 2 V lines per thread (16B each)
    int srow[2], sch[2];
#pragma unroll
    for (int s = 0; s < 2; s++) {
        int u = tid + 256 * s;
        srow[s] = u >> 3; sch[s] = u & 7;
    }
    const bf16* Ksrc = kn + ((size_t)(e * 2 + b) * NT + jbeg) * 64;
    const bf16* Vsrc = vT + (size_t)(pv * 2 + b) * 64 * NT + jbeg;

    // Q fragments (stage-1 B-operand), register resident
    bf16x8 Qf[2][2];
#pragma unroll
    for (int mt = 0; mt < 2; mt++)
#pragma unroll
        for (int hc = 0; hc < 2; hc++)
            Qf[mt][hc] = *(const bf16x8*)(qn +
                ((size_t)(qtv * 2 + b) * NT + qrow0 + wstrip + mt * 16 + l15) * 64 +
                hc * 32 + quad * 8);

    f32x4 acc2[4][2];   // [ht][mt]  (acc^T: row=h, col=query)
#pragma unroll
    for (int ht = 0; ht < 4; ht++)
#pragma unroll
        for (int mt = 0; mt < 2; mt++) {
            f32x4 z = {0.f, 0.f, 0.f, 0.f};
            acc2[ht][mt] = z;
        }

    const uint* mbase[2];
#pragma unroll
    for (int mt = 0; mt < 2; mt++)
        mbase[mt] = mb + (size_t)(e * NT + qrow0 + wstrip + mt * 16 + l15) * 128 + (jbeg >> 5);

    // ---- prologue: load iter0, write buf0, issue iter1 loads ----
    u32x4 kreg[2], vreg[2];
#pragma unroll
    for (int s = 0; s < 2; s++) {
        kreg[s] = *(const u32x4*)(Ksrc + (size_t)srow[s] * 64 + sch[s] * 8);
        vreg[s] = *(const u32x4*)(Vsrc + (size_t)srow[s] * NT + sch[s] * 8);
    }
    u32x2 mcur[2], mnxt[2];
#pragma unroll
    for (int mt = 0; mt < 2; mt++) {
        mcur[mt] = *(const u32x2*)(mbase[mt]);
        mnxt[mt] = *(const u32x2*)(mbase[mt] + ((NI > 1) ? 2 : 0));
    }
#pragma unroll
    for (int s = 0; s < 2; s++) {
        *(u32x4*)(&Klds[0][srow[s]][sch[s] * 8]) = kreg[s];
        *(u32x4*)(&Vlds[0][srow[s]][sch[s] * 8]) = vreg[s];
    }
    {
        const int j1 = (NI > 1) ? 64 : 0;
#pragma unroll
        for (int s = 0; s < 2; s++) {
            kreg[s] = *(const u32x4*)(Ksrc + (size_t)(j1 + srow[s]) * 64 + sch[s] * 8);
            vreg[s] = *(const u32x4*)(Vsrc + (size_t)srow[s] * NT + j1 + sch[s] * 8);
        }
    }
    __syncthreads();                               // buf0 visible

#pragma unroll 1
    for (int ji = 0; ji < NI; ji++) {
        const int cur = ji & 1;
        // prefetch mask bits for ji+2
        const int woff2 = (ji + 2 < NI) ? 2 * (ji + 2) : 0;
        u32x2 mtmp[2];
#pragma unroll
        for (int mt = 0; mt < 2; mt++)
            mtmp[mt] = *(const u32x2*)(mbase[mt] + woff2);

        // stage 1: S^T tiles from Klds[cur], mask via permuted bits, pack bf16
        uint Pd[4][2][2];    // [jt][mt][d]
#pragma unroll
        for (int jt = 0; jt < 4; jt++) {
            bf16x8 aK0 = *(const bf16x8*)(&Klds[cur][jt * 16 + l15][quad * 8]);
            bf16x8 aK1 = *(const bf16x8*)(&Klds[cur][jt * 16 + l15][32 + quad * 8]);
#pragma unroll
            for (int mt = 0; mt < 2; mt++) {
                f32x4 sc = {0.f, 0.f, 0.f, 0.f};
                sc = __builtin_amdgcn_mfma_f32_16x16x32_bf16(aK0, Qf[mt][0], sc, 0, 0, 0);
                sc = __builtin_amdgcn_mfma_f32_16x16x32_bf16(aK1, Qf[mt][1], sc, 0, 0, 0);
#pragma unroll
                for (int k = 0; k < 4; k++) {
                    const uint w = (k < 2) ? mcur[mt].x : mcur[mt].y;
                    sc[k] = ((w >> ((k & 1) * 16 + jt * 4 + quad)) & 1u) ? sc[k] : 0.0f;
                }
                Pd[jt][mt][0] = pack2(sc[0], sc[1]);
                Pd[jt][mt][1] = pack2(sc[2], sc[3]);
            }
        }
#pragma unroll
        for (int mt = 0; mt < 2; mt++) { mcur[mt] = mnxt[mt]; mnxt[mt] = mtmp[mt]; }

        // B-frags via permlane row-swaps
        uint Bf[2][2][4];    // [mt][c][v]
#pragma unroll
        for (int mt = 0; mt < 2; mt++)
#pragma unroll
            for (int c = 0; c < 2; c++)
#pragma unroll
                for (int d = 0; d < 2; d++) {
                    uint x = Pd[2 * c][mt][d];
                    uint y = Pd[2 * c + 1][mt][d];
                    asm("v_permlane32_swap_b32 %0, %1\n\t"
                        "v_permlane16_swap_b32 %0, %1"
                        : "+v"(x), "+v"(y));
                    Bf[mt][c][d]     = x;   // v = d
                    Bf[mt][c][d + 2] = y;   // v = d+2
                }

        // stage 2: acc^T += VT·P^T from Vlds[cur]
#pragma unroll
        for (int ht = 0; ht < 4; ht++)
#pragma unroll
            for (int c = 0; c < 2; c++) {
                bf16x8 a = *(const bf16x8*)(&Vlds[cur][ht * 16 + l15][c * 32 + quad * 8]);
#pragma unroll
                for (int mt = 0; mt < 2; mt++) {
                    u32x4 t = {Bf[mt][c][0], Bf[mt][c][1], Bf[mt][c][2], Bf[mt][c][3]};
                    bf16x8 bbv = __builtin_bit_cast(bf16x8, t);
                    acc2[ht][mt] =
                        __builtin_amdgcn_mfma_f32_16x16x32_bf16(a, bbv, acc2[ht][mt], 0, 0, 0);
                }
            }

        // write next buffer from prefetched regs, issue ji+2 loads, barrier
        if (ji + 1 < NI) {
            const int nxt = cur ^ 1;
#pragma unroll
            for (int s = 0; s < 2; s++) {
                *(u32x4*)(&Klds[nxt][srow[s]][sch[s] * 8]) = kreg[s];
                *(u32x4*)(&Vlds[nxt][srow[s]][sch[s] * 8]) = vreg[s];
            }
            const int j2 = (ji + 2 < NI) ? (ji + 2) * 64 : 0;
#pragma unroll
            for (int s = 0; s < 2; s++) {
                kreg[s] = *(const u32x4*)(Ksrc + (size_t)(j2 + srow[s]) * 64 + sch[s] * 8);
                vreg[s] = *(const u32x4*)(Vsrc + (size_t)srow[s] * NT + j2 + sch[s] * 8);
            }
            __syncthreads();
        }
    }

    // bf16 partial store: Pacc[chunk][e][b][n][h], one u16x4 (8B) per frag
#pragma unroll
    for (int ht = 0; ht < 4; ht++)
#pragma unroll
        for (int mt = 0; mt < 2; mt++) {
            const int n = qrow0 + wstrip + mt * 16 + l15;
            u16x4 pk;
#pragma unroll
            for (int r2 = 0; r2 < 4; r2++)
                pk[r2] = __builtin_bit_cast(unsigned short, (bf16)acc2[ht][mt][r2]);
            *(u16x4*)(Pacc + ((((size_t)(jcv * 6 + e) * 2 + b) * NT + n) << 6) +
                      ht * 16 + quad * 4) = pk;
        }
}

// ---------------------------------------------------------------------------
// Kernel 3: combine bf16 partials over JC chunks in fp32 (acc_t = ΣP/rowsum),
// dt_t = 2*sigmoid(h_t Wdt_t^T + b) - 1, h_tn = h_t + step*dt*u_t, outputs.
// Pacc bf16 [chunk][e][b][n][h]: per-thread bf16x8 loads (16B, h contiguous).
// Output columns split across 2 blocks (ih), grid 768.
// ---------------------------------------------------------------------------
template<int JC>
__global__ __launch_bounds__(256) void update_kernel(
    const float* __restrict__ x0, const float* __restrict__ h0,
    const float* __restrict__ h1, const float* __restrict__ h2,
    const float* __restrict__ Wsu0, const float* __restrict__ Wsu12,
    const float* __restrict__ Wdt, const float* __restrict__ bdt,
    const float* __restrict__ stepp, const float* __restrict__ oscp,
    const bf16* __restrict__ Pacc, const float* __restrict__ rs2,
    float* __restrict__ dout)
{
    const int tid = threadIdx.x, wid = tid >> 6, lane = tid & 63;
    const int l15 = lane & 15, quad = lane >> 4;
    const int bx = blockIdx.x;
    const int ih = (bx >= 384) ? 1 : 0;          // column half: it = ih*2 + ii
    const int base = bx - ih * 384;              // 0..383
    const int rt = base & 127, t = base >> 7;
    const int g0 = rt * 64;
    const int grow = g0 + wid * 16 + l15;
    const int n = grow & 4095, bb = grow >> 12;
    const float step = *stepp, osc = *oscp;
    const float* hs[3] = {h0, h1, h2};
    const float* __restrict__ ht_base = hs[t];

    bf16x8 afh[2], afacc[2], afx;
#pragma unroll
    for (int hc = 0; hc < 2; hc++)
        afh[hc] = ld8f(ht_base + (size_t)grow * 64 + hc * 32 + quad * 8);
    if (t == 0) afx = ld8f(x0 + (size_t)grow * 32 + quad * 8);

    const float i0 = 1.f / rs2[(size_t)(2 * t) * NT + n];
    const float i1 = 1.f / rs2[(size_t)(2 * t + 1) * NT + n];
#pragma unroll
    for (int hc = 0; hc < 2; hc++) {
        float S0[8] = {0,0,0,0,0,0,0,0}, S1[8] = {0,0,0,0,0,0,0,0};
#pragma unroll
        for (int jc = 0; jc < JC; jc++) {
            const bf16* p0 = Pacc + ((((size_t)(jc * 6 + 2 * t) * 2 + bb) * NT + n) << 6) +
                             hc * 32 + quad * 8;
            const bf16* p1 = Pacc + ((((size_t)(jc * 6 + 2 * t + 1) * 2 + bb) * NT + n) << 6) +
                             hc * 32 + quad * 8;
            bf16x8 v0 = *(const bf16x8*)p0;
            bf16x8 v1 = *(const bf16x8*)p1;
#pragma unroll
            for (int j = 0; j < 8; j++) { S0[j] += (float)v0[j]; S1[j] += (float)v1[j]; }
        }
        bf16x8 v;
#pragma unroll
        for (int j = 0; j < 8; j++) v[j] = (bf16)(S0[j] * i0 + S1[j] * i1);
        afacc[hc] = v;
    }

#pragma unroll
    for (int ii = 0; ii < 2; ii++) {
        const int it = ih * 2 + ii;
        const float bdtv = bdt[t * 64 + it * 16 + l15];
        f32x4 z = {0.f, 0.f, 0.f, 0.f};
        f32x4 u = {0.f, 0.f, 0.f, 0.f};
#pragma unroll
        for (int hc = 0; hc < 2; hc++) {
            bf16x8 wb = ld8f(Wdt + (size_t)t * 4096 + (size_t)(it * 16 + l15) * 64 + hc * 32 + quad * 8);
            z = __builtin_amdgcn_mfma_f32_16x16x32_bf16(afh[hc], wb, z, 0, 0, 0);
        }
        if (t == 0) {
            bf16x8 w0 = ld8f(Wsu0 + (size_t)(it * 16 + l15) * 96 + quad * 8);
            u = __builtin_amdgcn_mfma_f32_16x16x32_bf16(afx, w0, u, 0, 0, 0);
#pragma unroll
            for (int kc = 0; kc < 2; kc++) {
                bf16x8 wk = ld8f(Wsu0 + (size_t)(it * 16 + l15) * 96 + 32 + kc * 32 + quad * 8);
                u = __builtin_amdgcn_mfma_f32_16x16x32_bf16(afacc[kc], wk, u, 0, 0, 0);
            }
        } else {
#pragma unroll
            for (int kc = 0; kc < 2; kc++) {
                bf16x8 wk = ld8f(Wsu12 + (size_t)(t - 1) * 4096 + (size_t)(it * 16 + l15) * 64 + kc * 32 + quad * 8);
                u = __builtin_amdgcn_mfma_f32_16x16x32_bf16(afacc[kc], wk, u, 0, 0, 0);
            }
        }
        const int colg = it * 16 + l15;
#pragma unroll
        for (int r = 0; r < 4; r++) {
            int row = g0 + wid * 16 + quad * 4 + r;
            float zz = z[r] + bdtv;
            float dtv = 2.f / (1.f + __expf(-zz)) - 1.f;
            float hval = ht_base[(size_t)row * 64 + colg];
            float hn = hval + step * dtv * u[r];
            dout[65536 + (size_t)t * 524288 + (size_t)row * 64 + colg] = hn;
            if (t == 2 && colg < 8)
                dout[(size_t)row * 8 + colg] = osc * hn;
        }
    }
}

extern "C" void kernel_launch(void* const* d_in, const int* in_sizes, int n_in,
                              void* d_out, int out_size, void* d_ws, size_t ws_size,
                              hipStream_t stream) {
    const float* x0   = (const float*)d_in[0];
    const float* h0   = (const float*)d_in[1];
    const float* h1   = (const float*)d_in[2];
    const float* h2   = (const float*)d_in[3];
    const float* m00  = (const float*)d_in[4];
    const float* m20  = (const float*)d_in[5];
    const float* m01  = (const float*)d_in[6];
    const float* m11  = (const float*)d_in[7];
    const float* m12  = (const float*)d_in[8];
    const float* m22  = (const float*)d_in[9];
    const float* Wq   = (const float*)d_in[10];
    const float* Wk   = (const float*)d_in[11];
    const float* Wsu0 = (const float*)d_in[12];
    const float* Wsu12= (const float*)d_in[13];
    const float* Wdt  = (const float*)d_in[14];
    const float* bdt  = (const float*)d_in[15];
    const float* step = (const float*)d_in[16];
    const float* oscl = (const float*)d_in[17];

    // workspace layout (element counts)
    bf16* qn  = (bf16*)d_ws;                    // 3*2*4096*64 = 1,572,864
    bf16* kn  = qn + 1572864;                   // 6*2*4096*64 = 3,145,728
    bf16* vT  = kn + 3145728;                   // 3*2*64*4096 = 1,572,864
    uint* mb  = (uint*)(vT + 1572864);          // 6*4096*128  = 3,145,728 uints
    float* rs2 = (float*)(mb + 3145728);        // 6*4096      = 24,576 floats
    bf16* Pacc = (bf16*)(rs2 + 24576);          // JC*6*2*4096*64 bf16 [chunk][e][b][n][h]

    // bytes: 25,264,128 fixed + JC*6,291,456 (Pacc bf16)
    auto need = [](size_t jc) { return 25264128 + jc * 6291456; };
    const int JC = (ws_size >= need(4)) ? 4 : ((ws_size >= need(2)) ? 2 : 1);

    mask_kernel<<<6144, 256, 0, stream>>>(m00, m20, m01, m11, m12, m22, mb, rs2);
    prep_kernel<<<1536, 256, 0, stream>>>(h0, h1, h2, Wq, Wk, qn, kn, vT);

    if (JC == 4) {
        attn_kernel<4><<<6 * 32 * 2 * 4, 256, 0, stream>>>(qn, kn, vT, mb, Pacc);
        update_kernel<4><<<768, 256, 0, stream>>>(x0, h0, h1, h2, Wsu0, Wsu12, Wdt, bdt,
                                                  step, oscl, Pacc, rs2, (float*)d_out);
    } else if (JC == 2) {
        attn_kernel<2><<<6 * 32 * 2 * 2, 256, 0, stream>>>(qn, kn, vT, mb, Pacc);
        update_kernel<2><<<768, 256, 0, stream>>>(x0, h0, h1, h2, Wsu0, Wsu12, Wdt, bdt,
                                                  step, oscl, Pacc, rs2, (float*)d_out);
    } else {
        attn_kernel<1><<<6 * 32 * 2 * 1, 256, 0, stream>>>(qn, kn, vT, mb, Pacc);
        update_kernel<1><<<768, 256, 0, stream>>>(x0, h0, h1, h2, Wsu0, Wsu12, Wdt, bdt,
                                                  step, oscl, Pacc, rs2, (float*)d_out);
    }
}

// Round 9
// 459.710 us; speedup vs baseline: 1.1796x; 1.0350x over previous
//
#include <hip/hip_runtime.h>

typedef __bf16 bf16;
typedef bf16 bf16x8 __attribute__((ext_vector_type(8)));
typedef float f32x4 __attribute__((ext_vector_type(4)));
typedef unsigned int uint;
typedef uint u32x4 __attribute__((ext_vector_type(4)));
typedef unsigned short u16x4 __attribute__((ext_vector_type(4)));
typedef unsigned short u16x8 __attribute__((ext_vector_type(8)));

constexpr int NT = 4096;   // sequence length N
// H = 64, B = 2

__device__ __forceinline__ bf16x8 ld8f(const float* p) {
    f32x4 a = *(const f32x4*)p;
    f32x4 b = *(const f32x4*)(p + 4);
    bf16x8 v;
    v[0] = (bf16)a[0]; v[1] = (bf16)a[1]; v[2] = (bf16)a[2]; v[3] = (bf16)a[3];
    v[4] = (bf16)b[0]; v[5] = (bf16)b[1]; v[6] = (bf16)b[2]; v[7] = (bf16)b[3];
    return v;
}

__device__ __forceinline__ uint pack2(float a, float b) {
    unsigned short ua = __builtin_bit_cast(unsigned short, (bf16)a);
    unsigned short ub = __builtin_bit_cast(unsigned short, (bf16)b);
    return (uint)ua | ((uint)ub << 16);
}

// ---------------------------------------------------------------------------
// Kernel 1: grid = 1536. slices 0..8: one projection each (q0,q1,q2,k0..k5);
// slices 9..11: bf16 transpose vT for one pred each.
// ---------------------------------------------------------------------------
__global__ __launch_bounds__(256) void prep_kernel(
    const float* __restrict__ h0, const float* __restrict__ h1, const float* __restrict__ h2,
    const float* __restrict__ Wq, const float* __restrict__ Wk,
    bf16* __restrict__ qn, bf16* __restrict__ kn, bf16* __restrict__ vT)
{
    __shared__ __align__(16) unsigned short tlds[4][16][72];
    const int tid = threadIdx.x, wid = tid >> 6, lane = tid & 63;
    const int l15 = lane & 15, quad = lane >> 4;
    const int bx = blockIdx.x;
    const int rt = bx & 127, sl = bx >> 7;       // slice 0..11
    const int g0 = rt * 64;
    const int grow = g0 + wid * 16 + l15;        // A-frag row (global b*N+n)
    const float* hs[3] = {h0, h1, h2};
    const int predmap[6] = {0, 2, 0, 1, 1, 2};

    if (sl >= 9) {
        // ---- transpose slice: vT[p][b][h][n] ----
        const int p = sl - 9;
        bf16x8 af[2];
#pragma unroll
        for (int hc = 0; hc < 2; hc++)
            af[hc] = ld8f(hs[p] + (size_t)grow * 64 + hc * 32 + quad * 8);
#pragma unroll
        for (int hc = 0; hc < 2; hc++)
            *(u16x8*)(&tlds[wid][l15][hc * 32 + quad * 8]) = __builtin_bit_cast(u16x8, af[hc]);
        unsigned short vals[16];
#pragma unroll
        for (int r = 0; r < 16; r++) vals[r] = tlds[wid][r][lane];
        uint us[8];
#pragma unroll
        for (int k = 0; k < 8; k++) us[k] = (uint)vals[2 * k] | ((uint)vals[2 * k + 1] << 16);
        const int gr0 = g0 + wid * 16;
        const int bb = gr0 >> 12, n0 = gr0 & 4095;
        uint* dst = (uint*)(vT + ((size_t)(p * 2 + bb) * 64 + lane) * NT + n0);
        u32x4 w0 = {us[0], us[1], us[2], us[3]};
        u32x4 w1 = {us[4], us[5], us[6], us[7]};
        *(u32x4*)dst = w0;
        *(u32x4*)(dst + 4) = w1;
        return;
    }

    // ---- projection slice ----
    const int pj = sl;
    const float* W = (pj < 3) ? (Wq + pj * 4096) : (Wk + (pj - 3) * 4096);
    const int src = (pj < 3) ? pj : predmap[pj - 3];
    bf16* outp = (pj < 3) ? (qn + (size_t)pj * 2 * NT * 64)
                          : (kn + (size_t)(pj - 3) * 2 * NT * 64);
    bf16x8 af[2];
#pragma unroll
    for (int hc = 0; hc < 2; hc++)
        af[hc] = ld8f(hs[src] + (size_t)grow * 64 + hc * 32 + quad * 8);

    f32x4 s[4];
#pragma unroll
    for (int it = 0; it < 4; it++) {
        f32x4 acc = {0.f, 0.f, 0.f, 0.f};
#pragma unroll
        for (int hc = 0; hc < 2; hc++) {
            bf16x8 wb = ld8f(W + (size_t)(it * 16 + l15) * 64 + hc * 32 + quad * 8);
            acc = __builtin_amdgcn_mfma_f32_16x16x32_bf16(af[hc], wb, acc, 0, 0, 0);
        }
        s[it] = acc;
    }
#pragma unroll
    for (int r = 0; r < 4; r++) {
        float ss = s[0][r] * s[0][r] + s[1][r] * s[1][r] + s[2][r] * s[2][r] + s[3][r] * s[3][r];
        ss += __shfl_xor(ss, 1); ss += __shfl_xor(ss, 2);
        ss += __shfl_xor(ss, 4); ss += __shfl_xor(ss, 8);
        float rn = rsqrtf(ss);
        s[0][r] *= rn; s[1][r] *= rn; s[2][r] *= rn; s[3][r] *= rn;
    }
    const int rowbase = g0 + wid * 16 + quad * 4;
#pragma unroll
    for (int it = 0; it < 4; it++)
#pragma unroll
        for (int r = 0; r < 4; r++)
            outp[(size_t)(rowbase + r) * 64 + it * 16 + l15] = (bf16)s[it][r];
}

// ---------------------------------------------------------------------------
// Kernel 2: masked cosine attention — the R1-measured fused structure
// (182 µs): raw fp32 masks loaded in-kernel, single mask-register set with
// loads issued immediately after last use (issue->use gap ~1 iteration,
// hidden under stage-2 MFMA + next iteration's stage-1), single LDS buffer,
// 2 barriers, register-prefetched K/V staging, permlane B-frag exchange,
// in-kernel rowsums. ONLY change vs R1: Pacc stored as BF16 (u16x4/frag).
// VGPR ~84 -> 3 blocks/CU (LB 256,3).
// grid = 6 edges * 32 q-tiles(128 rows) * JC.
// ---------------------------------------------------------------------------
template<int JC>
__global__ __launch_bounds__(256, 3) void attn_kernel(
    const bf16* __restrict__ qn, const bf16* __restrict__ kn, const bf16* __restrict__ vT,
    const float* __restrict__ m00, const float* __restrict__ m20, const float* __restrict__ m01,
    const float* __restrict__ m11, const float* __restrict__ m12, const float* __restrict__ m22,
    bf16* __restrict__ Pacc, float* __restrict__ rsO)
{
    __shared__ __align__(16) bf16 Klds[2][64][72];
    __shared__ __align__(16) bf16 Vlds[2][64][72];
    const int tid = threadIdx.x, wid = tid >> 6, lane = tid & 63;
    const int l15 = lane & 15, quad = lane >> 4;
    const int bx = blockIdx.x;
    const int e = bx / (32 * JC);
    const int rem = bx % (32 * JC);
    const int qt = rem / JC, jcv = rem % JC;
    const int qrow0 = qt * 128, wstrip = wid * 32;
    const int qtypemap[6] = {0, 0, 1, 1, 2, 2};
    const int predmap[6]  = {0, 2, 0, 1, 1, 2};
    const float* masks[6] = {m00, m20, m01, m11, m12, m22};
    const float* __restrict__ mask = masks[e];
    const int qtv = qtypemap[e], pv = predmap[e];
    constexpr int JSPAN = NT / JC;
    constexpr int NI = JSPAN / 64;
    const int jbeg = jcv * JSPAN;

    // per-thread staging line mapping (4 K lines + 4 V lines per thread)
    int s_b[4], s_jl[4], s_ch[4];
#pragma unroll
    for (int i = 0; i < 4; i++) {
        int u = tid + 256 * i;
        s_b[i] = u >> 9; s_jl[i] = (u >> 3) & 63; s_ch[i] = u & 7;
    }

    // Q fragments (stage-1 B-operand), register resident
    bf16x8 Qf[2][2][2];
#pragma unroll
    for (int b = 0; b < 2; b++)
#pragma unroll
        for (int mt = 0; mt < 2; mt++)
#pragma unroll
            for (int hc = 0; hc < 2; hc++)
                Qf[b][mt][hc] = *(const bf16x8*)(qn +
                    ((size_t)(qtv * 2 + b) * NT + qrow0 + wstrip + mt * 16 + l15) * 64 +
                    hc * 32 + quad * 8);

    f32x4 acc2[2][4][2];   // [b][ht][mt]  (acc^T: row=h, col=query)
#pragma unroll
    for (int b = 0; b < 2; b++)
#pragma unroll
        for (int ht = 0; ht < 4; ht++)
#pragma unroll
            for (int mt = 0; mt < 2; mt++) {
                f32x4 z = {0.f, 0.f, 0.f, 0.f};
                acc2[b][ht][mt] = z;
            }
    float rsl[2] = {0.f, 0.f};

    // ---- preload staging + mask regs for first iteration ----
    u32x4 kreg[4], vreg[4];
#pragma unroll
    for (int i = 0; i < 4; i++) {
        kreg[i] = *(const u32x4*)(kn + ((size_t)(e * 2 + s_b[i]) * NT + jbeg + s_jl[i]) * 64 + s_ch[i] * 8);
        vreg[i] = *(const u32x4*)(vT + ((size_t)(pv * 2 + s_b[i]) * 64 + s_jl[i]) * NT + jbeg + s_ch[i] * 8);
    }
    f32x4 mv[2][4];
#pragma unroll
    for (int mt = 0; mt < 2; mt++)
#pragma unroll
        for (int jt = 0; jt < 4; jt++)
            mv[mt][jt] = *(const f32x4*)(mask +
                (size_t)(qrow0 + wstrip + mt * 16 + l15) * NT + jbeg + jt * 16 + quad * 4);

#pragma unroll 1
    for (int ji = 0; ji < NI; ji++) {
        const int jn = (ji + 1 < NI) ? (jbeg + (ji + 1) * 64) : jbeg;   // next (clamped)

        __syncthreads();                           // prior compute done reading LDS
#pragma unroll
        for (int i = 0; i < 4; i++) {
            *(u32x4*)(&Klds[s_b[i]][s_jl[i]][s_ch[i] * 8]) = kreg[i];
            *(u32x4*)(&Vlds[s_b[i]][s_jl[i]][s_ch[i] * 8]) = vreg[i];
        }
        __syncthreads();                           // staged tile visible

        // issue next iteration's staging loads — in flight during compute
#pragma unroll
        for (int i = 0; i < 4; i++) {
            kreg[i] = *(const u32x4*)(kn + ((size_t)(e * 2 + s_b[i]) * NT + jn + s_jl[i]) * 64 + s_ch[i] * 8);
            vreg[i] = *(const u32x4*)(vT + ((size_t)(pv * 2 + s_b[i]) * 64 + s_jl[i]) * NT + jn + s_ch[i] * 8);
        }

        // mask rowsums (current mv)
#pragma unroll
        for (int mt = 0; mt < 2; mt++)
#pragma unroll
            for (int jt = 0; jt < 4; jt++)
                rsl[mt] += mv[mt][jt][0] + mv[mt][jt][1] + mv[mt][jt][2] + mv[mt][jt][3];

        // stage 1 for BOTH batches: S^T tiles, mask, pack bf16 pairs
        uint Pd[2][4][2][2];    // [b][jt][mt][d]
#pragma unroll
        for (int jt = 0; jt < 4; jt++)
#pragma unroll
            for (int b = 0; b < 2; b++) {
                bf16x8 aK0 = *(const bf16x8*)(&Klds[b][jt * 16 + l15][quad * 8]);
                bf16x8 aK1 = *(const bf16x8*)(&Klds[b][jt * 16 + l15][32 + quad * 8]);
#pragma unroll
                for (int mt = 0; mt < 2; mt++) {
                    f32x4 sc = {0.f, 0.f, 0.f, 0.f};
                    sc = __builtin_amdgcn_mfma_f32_16x16x32_bf16(aK0, Qf[b][mt][0], sc, 0, 0, 0);
                    sc = __builtin_amdgcn_mfma_f32_16x16x32_bf16(aK1, Qf[b][mt][1], sc, 0, 0, 0);
                    sc[0] *= mv[mt][jt][0]; sc[1] *= mv[mt][jt][1];
                    sc[2] *= mv[mt][jt][2]; sc[3] *= mv[mt][jt][3];
                    Pd[b][jt][mt][0] = pack2(sc[0], sc[1]);
                    Pd[b][jt][mt][1] = pack2(sc[2], sc[3]);
                }
            }

        // mv's last use is above — issue next iteration's mask loads now
#pragma unroll
        for (int mt = 0; mt < 2; mt++)
#pragma unroll
            for (int jt = 0; jt < 4; jt++)
                mv[mt][jt] = *(const f32x4*)(mask +
                    (size_t)(qrow0 + wstrip + mt * 16 + l15) * NT + jn + jt * 16 + quad * 4);

        // stage 2 per batch: B-frags via permlane row-swaps, then acc^T += VT·P^T
#pragma unroll
        for (int b = 0; b < 2; b++) {
            uint Bf[2][2][4];    // [mt][c][v]
#pragma unroll
            for (int mt = 0; mt < 2; mt++)
#pragma unroll
                for (int c = 0; c < 2; c++)
#pragma unroll
                    for (int d = 0; d < 2; d++) {
                        uint x = Pd[b][2 * c][mt][d];
                        uint y = Pd[b][2 * c + 1][mt][d];
                        asm("v_permlane32_swap_b32 %0, %1\n\t"
                            "v_permlane16_swap_b32 %0, %1"
                            : "+v"(x), "+v"(y));
                        Bf[mt][c][d]     = x;   // v = d
                        Bf[mt][c][d + 2] = y;   // v = d+2
                    }
#pragma unroll
            for (int ht = 0; ht < 4; ht++)
#pragma unroll
                for (int c = 0; c < 2; c++) {
                    bf16x8 a = *(const bf16x8*)(&Vlds[b][ht * 16 + l15][c * 32 + quad * 8]);
#pragma unroll
                    for (int mt = 0; mt < 2; mt++) {
                        u32x4 t = {Bf[mt][c][0], Bf[mt][c][1], Bf[mt][c][2], Bf[mt][c][3]};
                        bf16x8 bbv = __builtin_bit_cast(bf16x8, t);
                        acc2[b][ht][mt] =
                            __builtin_amdgcn_mfma_f32_16x16x32_bf16(a, bbv, acc2[b][ht][mt], 0, 0, 0);
                    }
                }
        }
    }

    // bf16 partial store: Pacc[chunk][e][b][n][h], one u16x4 (8B) per frag
#pragma unroll
    for (int b = 0; b < 2; b++)
#pragma unroll
        for (int ht = 0; ht < 4; ht++)
#pragma unroll
            for (int mt = 0; mt < 2; mt++) {
                const int n = qrow0 + wstrip + mt * 16 + l15;
                u16x4 pk;
#pragma unroll
                for (int r2 = 0; r2 < 4; r2++)
                    pk[r2] = __builtin_bit_cast(unsigned short, (bf16)acc2[b][ht][mt][r2]);
                *(u16x4*)(Pacc + ((((size_t)(jcv * 6 + e) * 2 + b) * NT + n) << 6) +
                          ht * 16 + quad * 4) = pk;
            }
    // mask rowsums: quads hold disjoint j segments
#pragma unroll
    for (int mt = 0; mt < 2; mt++) {
        float v = rsl[mt];
        v += __shfl_xor(v, 16);
        v += __shfl_xor(v, 32);
        if (quad == 0)
            rsO[(size_t)(jcv * 6 + e) * NT + qrow0 + wstrip + mt * 16 + l15] = v;
    }
}

// ---------------------------------------------------------------------------
// Kernel 3: combine bf16 partials over JC chunks in fp32 (acc_t = ΣP/Σrs),
// dt_t = 2*sigmoid(h_t Wdt_t^T + b) - 1, h_tn = h_t + step*dt*u_t, outputs.
// Pacc bf16 [chunk][e][b][n][h]: bf16x8 loads. rs summed over chunks.
// Output columns split across 2 blocks (ih), grid 768.
// ---------------------------------------------------------------------------
template<int JC>
__global__ __launch_bounds__(256) void update_kernel(
    const float* __restrict__ x0, const float* __restrict__ h0,
    const float* __restrict__ h1, const float* __restrict__ h2,
    const float* __restrict__ Wsu0, const float* __restrict__ Wsu12,
    const float* __restrict__ Wdt, const float* __restrict__ bdt,
    const float* __restrict__ stepp, const float* __restrict__ oscp,
    const bf16* __restrict__ Pacc, const float* __restrict__ rs,
    float* __restrict__ dout)
{
    const int tid = threadIdx.x, wid = tid >> 6, lane = tid & 63;
    const int l15 = lane & 15, quad = lane >> 4;
    const int bx = blockIdx.x;
    const int ih = (bx >= 384) ? 1 : 0;          // column half: it = ih*2 + ii
    const int base = bx - ih * 384;              // 0..383
    const int rt = base & 127, t = base >> 7;
    const int g0 = rt * 64;
    const int grow = g0 + wid * 16 + l15;
    const int n = grow & 4095, bb = grow >> 12;
    const float step = *stepp, osc = *oscp;
    const float* hs[3] = {h0, h1, h2};
    const float* __restrict__ ht_base = hs[t];

    bf16x8 afh[2], afacc[2], afx;
#pragma unroll
    for (int hc = 0; hc < 2; hc++)
        afh[hc] = ld8f(ht_base + (size_t)grow * 64 + hc * 32 + quad * 8);
    if (t == 0) afx = ld8f(x0 + (size_t)grow * 32 + quad * 8);

    float s0 = 0.f, s1 = 0.f;
#pragma unroll
    for (int jc = 0; jc < JC; jc++) {
        s0 += rs[(size_t)(jc * 6 + 2 * t) * NT + n];
        s1 += rs[(size_t)(jc * 6 + 2 * t + 1) * NT + n];
    }
    const float i0 = 1.f / s0, i1 = 1.f / s1;
#pragma unroll
    for (int hc = 0; hc < 2; hc++) {
        float S0[8] = {0,0,0,0,0,0,0,0}, S1[8] = {0,0,0,0,0,0,0,0};
#pragma unroll
        for (int jc = 0; jc < JC; jc++) {
            const bf16* p0 = Pacc + ((((size_t)(jc * 6 + 2 * t) * 2 + bb) * NT + n) << 6) +
                             hc * 32 + quad * 8;
            const bf16* p1 = Pacc + ((((size_t)(jc * 6 + 2 * t + 1) * 2 + bb) * NT + n) << 6) +
                             hc * 32 + quad * 8;
            bf16x8 v0 = *(const bf16x8*)p0;
            bf16x8 v1 = *(const bf16x8*)p1;
#pragma unroll
            for (int j = 0; j < 8; j++) { S0[j] += (float)v0[j]; S1[j] += (float)v1[j]; }
        }
        bf16x8 v;
#pragma unroll
        for (int j = 0; j < 8; j++) v[j] = (bf16)(S0[j] * i0 + S1[j] * i1);
        afacc[hc] = v;
    }

#pragma unroll
    for (int ii = 0; ii < 2; ii++) {
        const int it = ih * 2 + ii;
        const float bdtv = bdt[t * 64 + it * 16 + l15];
        f32x4 z = {0.f, 0.f, 0.f, 0.f};
        f32x4 u = {0.f, 0.f, 0.f, 0.f};
#pragma unroll
        for (int hc = 0; hc < 2; hc++) {
            bf16x8 wb = ld8f(Wdt + (size_t)t * 4096 + (size_t)(it * 16 + l15) * 64 + hc * 32 + quad * 8);
            z = __builtin_amdgcn_mfma_f32_16x16x32_bf16(afh[hc], wb, z, 0, 0, 0);
        }
        if (t == 0) {
            bf16x8 w0 = ld8f(Wsu0 + (size_t)(it * 16 + l15) * 96 + quad * 8);
            u = __builtin_amdgcn_mfma_f32_16x16x32_bf16(afx, w0, u, 0, 0, 0);
#pragma unroll
            for (int kc = 0; kc < 2; kc++) {
                bf16x8 wk = ld8f(Wsu0 + (size_t)(it * 16 + l15) * 96 + 32 + kc * 32 + quad * 8);
                u = __builtin_amdgcn_mfma_f32_16x16x32_bf16(afacc[kc], wk, u, 0, 0, 0);
            }
        } else {
#pragma unroll
            for (int kc = 0; kc < 2; kc++) {
                bf16x8 wk = ld8f(Wsu12 + (size_t)(t - 1) * 4096 + (size_t)(it * 16 + l15) * 64 + kc * 32 + quad * 8);
                u = __builtin_amdgcn_mfma_f32_16x16x32_bf16(afacc[kc], wk, u, 0, 0, 0);
            }
        }
        const int colg = it * 16 + l15;
#pragma unroll
        for (int r = 0; r < 4; r++) {
            int row = g0 + wid * 16 + quad * 4 + r;
            float zz = z[r] + bdtv;
            float dtv = 2.f / (1.f + __expf(-zz)) - 1.f;
            float hval = ht_base[(size_t)row * 64 + colg];
            float hn = hval + step * dtv * u[r];
            dout[65536 + (size_t)t * 524288 + (size_t)row * 64 + colg] = hn;
            if (t == 2 && colg < 8)
                dout[(size_t)row * 8 + colg] = osc * hn;
        }
    }
}

extern "C" void kernel_launch(void* const* d_in, const int* in_sizes, int n_in,
                              void* d_out, int out_size, void* d_ws, size_t ws_size,
                              hipStream_t stream) {
    const float* x0   = (const float*)d_in[0];
    const float* h0   = (const float*)d_in[1];
    const float* h1   = (const float*)d_in[2];
    const float* h2   = (const float*)d_in[3];
    const float* m00  = (const float*)d_in[4];
    const float* m20  = (const float*)d_in[5];
    const float* m01  = (const float*)d_in[6];
    const float* m11  = (const float*)d_in[7];
    const float* m12  = (const float*)d_in[8];
    const float* m22  = (const float*)d_in[9];
    const float* Wq   = (const float*)d_in[10];
    const float* Wk   = (const float*)d_in[11];
    const float* Wsu0 = (const float*)d_in[12];
    const float* Wsu12= (const float*)d_in[13];
    const float* Wdt  = (const float*)d_in[14];
    const float* bdt  = (const float*)d_in[15];
    const float* step = (const float*)d_in[16];
    const float* oscl = (const float*)d_in[17];

    // workspace layout (element counts)
    bf16* qn  = (bf16*)d_ws;                    // 3*2*4096*64 = 1,572,864
    bf16* kn  = qn + 1572864;                   // 6*2*4096*64 = 3,145,728
    bf16* vT  = kn + 3145728;                   // 3*2*64*4096 = 1,572,864
    float* rs = (float*)(vT + 1572864);         // JC*6*4096 floats
    // Pacc (bf16) follows rs: JC*6*2*4096*64 bf16 [chunk][e][b][n][h]

    // bytes: 12,582,912 fixed + JC*98,304 (rs) + JC*6,291,456 (Pacc bf16)
    auto need = [](size_t jc) { return 12582912 + jc * 98304 + jc * 6291456; };
    const int JC = (ws_size >= need(4)) ? 4 : ((ws_size >= need(2)) ? 2 : 1);
    bf16* Pacc = (bf16*)(rs + (size_t)JC * 24576);

    prep_kernel<<<1536, 256, 0, stream>>>(h0, h1, h2, Wq, Wk, qn, kn, vT);

    if (JC == 4) {
        attn_kernel<4><<<6 * 32 * 4, 256, 0, stream>>>(qn, kn, vT, m00, m20, m01, m11, m12, m22, Pacc, rs);
        update_kernel<4><<<768, 256, 0, stream>>>(x0, h0, h1, h2, Wsu0, Wsu12, Wdt, bdt,
                                                  step, oscl, Pacc, rs, (float*)d_out);
    } else if (JC == 2) {
        attn_kernel<2><<<6 * 32 * 2, 256, 0, stream>>>(qn, kn, vT, m00, m20, m01, m11, m12, m22, Pacc, rs);
        update_kernel<2><<<768, 256, 0, stream>>>(x0, h0, h1, h2, Wsu0, Wsu12, Wdt, bdt,
                                                  step, oscl, Pacc, rs, (float*)d_out);
    } else {
        attn_kernel<1><<<6 * 32 * 1, 256, 0, stream>>>(qn, kn, vT, m00, m20, m01, m11, m12, m22, Pacc, rs);
        update_kernel<1><<<768, 256, 0, stream>>>(x0, h0, h1, h2, Wsu0, Wsu12, Wdt, bdt,
                                                  step, oscl, Pacc, rs, (float*)d_out);
    }
}